// Round 4
// baseline (248.245 us; speedup 1.0000x reference)
//
#include <hip/hip_runtime.h>
#include <math.h>

#define TL 2048
#define TD 768
#define NH 12
#define HD 64
#define NB 4
#define MTOT (NB * TL)   // 8192

typedef __bf16 bf16;
typedef __attribute__((ext_vector_type(4))) __bf16 bf16x4;
typedef __attribute__((ext_vector_type(8))) __bf16 bf16x8;
typedef __attribute__((ext_vector_type(4))) float floatx4;

// Q pre-scale: 1/sqrt(64) * log2(e)  (softmax computed in exp2 domain)
#define QSCALE 0.18033688011112042f

#define MFMA16(A, B, C) __builtin_amdgcn_mfma_f32_16x16x32_bf16(A, B, C, 0, 0, 0)

__device__ __forceinline__ void gl_lds16(const void* g, void* l) {
    __builtin_amdgcn_global_load_lds(
        (const __attribute__((address_space(1))) void*)g,
        (__attribute__((address_space(3))) void*)l, 16, 0, 0);
}

__device__ __forceinline__ floatx4 exp2x4(floatx4 a) {
    floatx4 r;
    r.x = __builtin_amdgcn_exp2f(a.x);
    r.y = __builtin_amdgcn_exp2f(a.y);
    r.z = __builtin_amdgcn_exp2f(a.z);
    r.w = __builtin_amdgcn_exp2f(a.w);
    return r;
}

// Inverse of the key->LDS-row permutation that makes QK^T's C-registers
// coincide with PV's A-fragment layout. Row r holds key kperm_inv(r).
//   row bits [k5 k2 k4 k3 k1 k0] -> key
__device__ __forceinline__ int kperm_inv(int r) {
    return (r & 35) | (((r >> 2) & 3) << 3) | (((r >> 4) & 1) << 2);
}

// ---------------------------------------------------------------------------
// prep: fused x fp32->bf16 cast (blocks 0..6143) + W transpose->bf16
// (blocks 6144..6719). One launch instead of two.
// ---------------------------------------------------------------------------
__global__ __launch_bounds__(256)
void prep_kernel(const float* __restrict__ x, bf16* __restrict__ xb,
                 const float* __restrict__ W0, const float* __restrict__ W1,
                 const float* __restrict__ W2, const float* __restrict__ W3,
                 bf16* __restrict__ T0, bf16* __restrict__ T1,
                 bf16* __restrict__ T2, bf16* __restrict__ T3)
{
    __shared__ float Ts[64][65];
    const int t = threadIdx.x;

    if (blockIdx.x < 6144) {
        size_t i = ((size_t)blockIdx.x * 256 + t) * 4;
        float4 v = *(const float4*)(x + i);
        bf16x4 o;
        o[0] = (bf16)v.x; o[1] = (bf16)v.y; o[2] = (bf16)v.z; o[3] = (bf16)v.w;
        *(bf16x4*)(xb + i) = o;
        return;
    }

    const int bid = blockIdx.x - 6144;          // 0..575
    const int z = bid / 144, rem = bid % 144;
    const float* W = z == 0 ? W0 : z == 1 ? W1 : z == 2 ? W2 : W3;
    bf16*       T = z == 0 ? T0 : z == 1 ? T1 : z == 2 ? T2 : T3;
    const int k0 = (rem % 12) * 64, n0 = (rem / 12) * 64;
    const int rr = t >> 4, cc = (t & 15) * 4;
#pragma unroll
    for (int i = 0; i < 4; ++i) {
        int row = rr + i * 16;
        float4 v = *(const float4*)(W + (size_t)(k0 + row) * TD + n0 + cc);
        Ts[row][cc] = v.x; Ts[row][cc + 1] = v.y;
        Ts[row][cc + 2] = v.z; Ts[row][cc + 3] = v.w;
    }
    __syncthreads();
#pragma unroll
    for (int i = 0; i < 4; ++i) {
        int n = rr + i * 16;
        bf16x4 pk;
#pragma unroll
        for (int j = 0; j < 4; ++j) pk[j] = (bf16)Ts[cc + j][n];
        *(bf16x4*)(T + (size_t)(n0 + n) * TD + k0 + cc) = pk;
    }
}

// ---------------------------------------------------------------------------
// QKV GEMM: 128x128 tile, BK=64 (12 K-iters), XOR-swizzled LDS (no pad),
// global_load_lds staging, LDS-bounce coalesced epilogue.
// Epilogue bounce ALIASED onto As (safe after the final barrier) -> LDS
// 32 KB; __launch_bounds__(256,4) caps VGPR at 128 -> 4 blocks/CU resident.
// Q,K -> [bh][l][64] bf16 (Q pre-scaled by QSCALE); V -> [bh][d][2048] bf16.
// ---------------------------------------------------------------------------
__global__ __launch_bounds__(256, 4)
void qkv_gemm(const bf16* __restrict__ xb,
              const bf16* __restrict__ Wqt, const bf16* __restrict__ Wkt,
              const bf16* __restrict__ Wvt,
              const float* __restrict__ bq, const float* __restrict__ bk,
              const float* __restrict__ bv,
              bf16* __restrict__ Q, bf16* __restrict__ K, bf16* __restrict__ Vt)
{
    __shared__ __align__(16) bf16 SM[2 * 128 * 64];   // As | Bs ; epilogue reuses
    bf16* As = SM;
    bf16* Bs = SM + 128 * 64;

    const int t = threadIdx.x;
    const int lane = t & 63, w = t >> 6;
    const int quad = lane >> 4, l16 = lane & 15;
    const int m0 = blockIdx.x * 128;
    const int n0 = blockIdx.y * 128;
    const int which = blockIdx.z;
    const bf16*  W    = which == 0 ? Wqt : which == 1 ? Wkt : Wvt;
    const float* bias = which == 0 ? bq  : which == 1 ? bk  : bv;
    const float scale = which == 0 ? QSCALE : 1.0f;

    const int rm = (w >> 1) * 64, cn = (w & 1) * 64;

    floatx4 acc[4][4];
#pragma unroll
    for (int i = 0; i < 4; ++i)
#pragma unroll
        for (int j = 0; j < 4; ++j) acc[i][j] = (floatx4){0.f, 0.f, 0.f, 0.f};

    // staging sources: slot n = t + i*256; row = n>>3; seg = (n&7)^(row&7)
    const bf16* gA[4];
    const bf16* gB[4];
#pragma unroll
    for (int i = 0; i < 4; ++i) {
        int n = t + i * 256, r = n >> 3, s = ((n & 7) ^ (r & 7)) * 8;
        gA[i] = xb + (size_t)(m0 + r) * TD + s;
        gB[i] = W + (size_t)(n0 + r) * TD + s;
    }

    for (int kk = 0; kk < TD; kk += 64) {
#pragma unroll
        for (int i = 0; i < 4; ++i) {
            gl_lds16(gA[i] + kk, As + t * 8 + i * 2048);
            gl_lds16(gB[i] + kk, Bs + t * 8 + i * 2048);
        }
        __syncthreads();
#pragma unroll
        for (int ks = 0; ks < 2; ++ks) {
            bf16x8 af[4], bfr[4];
#pragma unroll
            for (int mb = 0; mb < 4; ++mb) {
                int r = rm + mb * 16 + l16;
                af[mb] = *(const bf16x8*)&As[r * 64 + (((ks * 4 + quad) ^ (r & 7)) * 8)];
            }
#pragma unroll
            for (int nb = 0; nb < 4; ++nb) {
                int r = cn + nb * 16 + l16;
                bfr[nb] = *(const bf16x8*)&Bs[r * 64 + (((ks * 4 + quad) ^ (r & 7)) * 8)];
            }
#pragma unroll
            for (int mb = 0; mb < 4; ++mb)
#pragma unroll
                for (int nb = 0; nb < 4; ++nb)
                    acc[mb][nb] = MFMA16(af[mb], bfr[nb], acc[mb][nb]);
        }
        __syncthreads();
    }

    float bsc[4];
#pragma unroll
    for (int nb = 0; nb < 4; ++nb)
        bsc[nb] = bias[n0 + cn + nb * 16 + l16] * scale;

    const int token0 = m0 + rm;
    const int b  = token0 >> 11;
    const int l0 = token0 & (TL - 1);
    const int h  = (n0 + cn) >> 6;
    const int bh = b * NH + h;
    // per-wave epilogue bounce region aliased onto SM (all LDS reads of the
    // K-loop completed before the final barrier above; regions are
    // wave-private so no further barrier is needed)
    bf16* Ew = SM + w * (16 * 72);

    if (which < 2) {
        bf16* gp = (which == 0 ? Q : K) + ((size_t)bh * TL + l0) * HD;
#pragma unroll
        for (int mb = 0; mb < 4; ++mb) {
#pragma unroll
            for (int nb = 0; nb < 4; ++nb)
#pragma unroll
                for (int r = 0; r < 4; ++r)
                    Ew[(quad * 4 + r) * 72 + nb * 16 + l16] =
                        (bf16)(acc[mb][nb][r] * scale + bsc[nb]);
#pragma unroll
            for (int i = 0; i < 2; ++i) {
                int row = i * 8 + (lane >> 3), seg = lane & 7;
                bf16x8 v = *(const bf16x8*)&Ew[row * 72 + seg * 8];
                *(bf16x8*)(gp + (size_t)(mb * 16 + row) * HD + seg * 8) = v;
            }
        }
    } else {
#pragma unroll
        for (int nb = 0; nb < 4; ++nb) {
#pragma unroll
            for (int mb = 0; mb < 4; ++mb) {
                bf16x4 pk;
#pragma unroll
                for (int r = 0; r < 4; ++r) pk[r] = (bf16)(acc[mb][nb][r] + bsc[nb]);
                *(bf16x4*)&Ew[l16 * 72 + mb * 16 + quad * 4] = pk;
            }
#pragma unroll
            for (int i = 0; i < 2; ++i) {
                int row = i * 8 + (lane >> 3), seg = lane & 7;
                bf16x8 v = *(const bf16x8*)&Ew[row * 72 + seg * 8];
                *(bf16x8*)(Vt + ((size_t)bh * HD + nb * 16 + row) * TL + l0 + seg * 8) = v;
            }
        }
    }
}

// ---------------------------------------------------------------------------
// MFMA flash attention v5 (round-0 exact): P never touches LDS; K/V staged
// via global_load_lds with the key permutation folded into the per-lane
// global source address and XOR segment swizzle instead of padding.
// ---------------------------------------------------------------------------
__global__ __launch_bounds__(256)
void attn_kernel(const bf16* __restrict__ Q, const bf16* __restrict__ K,
                 const bf16* __restrict__ Vt, bf16* __restrict__ O)
{
    __shared__ __align__(16) bf16 Ks[64 * 64];   // [kperm(key)][seg^(row&7)]
    __shared__ __align__(16) bf16 Vs[64 * 64];   // [d][seg^(d&7)] over keys

    const int t = threadIdx.x;
    const int lane = t & 63, w = t >> 6;
    const int quad = lane >> 4, l16 = lane & 15;

    // XCD-aware swizzle: blocks on the same XCD (n%8) share one bh's K/V
    const int n = blockIdx.y * gridDim.x + blockIdx.x;   // 0..767
    const int xcd = n & 7, s = n >> 3;                   // s: 0..95
    const int bh = xcd * 6 + (s >> 4);
    const int q0 = (s & 15) * 128;

    const bf16* Qb = Q + (size_t)bh * TL * HD;
    const bf16* Kb = K + (size_t)bh * TL * HD;
    const bf16* Vb = Vt + (size_t)bh * HD * TL;

    const int qw = q0 + w * 32;
    bf16x8 qf[2][2];
#pragma unroll
    for (int mb = 0; mb < 2; ++mb)
#pragma unroll
        for (int ks = 0; ks < 2; ++ks)
            qf[mb][ks] = *(const bf16x8*)(Qb + (size_t)(qw + mb * 16 + l16) * HD
                                          + ks * 32 + quad * 8);

    float lrow[2] = {0.f, 0.f};      // per-lane partial row-sum for q = mb*16+l16
    floatx4 o[2][4];
#pragma unroll
    for (int mb = 0; mb < 2; ++mb)
#pragma unroll
        for (int db = 0; db < 4; ++db) o[mb][db] = (floatx4){0.f, 0.f, 0.f, 0.f};

    // staging sources: slots n = t (i=0), t+256 (i=1); row = n>>3, 8 slots/row
    const bf16* gK[2];
    const bf16* gV[2];
#pragma unroll
    for (int i = 0; i < 2; ++i) {
        int nn = t + i * 256, r = nn >> 3, sg = ((nn & 7) ^ (r & 7)) * 8;
        gK[i] = Kb + (size_t)kperm_inv(r) * HD + sg;   // + k0*HD per step
        gV[i] = Vb + (size_t)r * TL + sg;              // + k0 per step
    }

    for (int kt = 0; kt < TL / 64; ++kt) {
        const int k0 = kt * 64;
        __syncthreads();
#pragma unroll
        for (int i = 0; i < 2; ++i) {
            gl_lds16(gK[i] + (size_t)k0 * HD, Ks + t * 8 + i * 2048);
            gl_lds16(gV[i] + k0,              Vs + t * 8 + i * 2048);
        }
        __syncthreads();

        // S^T = K' Q^T : lane holds S[q=mb*16+l16][key=32(nb>>1)+4(nb&1)+8quad+r]
        floatx4 s2[2][4];
#pragma unroll
        for (int nb = 0; nb < 4; ++nb) {
            int r = nb * 16 + l16;
            bf16x8 kf0 = *(const bf16x8*)&Ks[r * 64 + ((quad ^ (r & 7)) * 8)];
            bf16x8 kf1 = *(const bf16x8*)&Ks[r * 64 + (((4 + quad) ^ (r & 7)) * 8)];
#pragma unroll
            for (int mb = 0; mb < 2; ++mb) {
                floatx4 a = (floatx4){0.f, 0.f, 0.f, 0.f};
                a = MFMA16(kf0, qf[mb][0], a);
                a = MFMA16(kf1, qf[mb][1], a);
                s2[mb][nb] = a;
            }
        }

        // P = 2^S in-register; repack into PV A-fragments (keys ks*32+8quad+j)
        bf16x8 pA[2][2];
#pragma unroll
        for (int mb = 0; mb < 2; ++mb) {
#pragma unroll
            for (int ks = 0; ks < 2; ++ks) {
                floatx4 p0 = exp2x4(s2[mb][2 * ks]);
                floatx4 p1 = exp2x4(s2[mb][2 * ks + 1]);
                lrow[mb] += (p0.x + p0.y + p0.z + p0.w) + (p1.x + p1.y + p1.z + p1.w);
                bf16x8 pk;
                pk[0] = (bf16)p0.x; pk[1] = (bf16)p0.y; pk[2] = (bf16)p0.z; pk[3] = (bf16)p0.w;
                pk[4] = (bf16)p1.x; pk[5] = (bf16)p1.y; pk[6] = (bf16)p1.z; pk[7] = (bf16)p1.w;
                pA[mb][ks] = pk;
            }
        }

        // O += P V
#pragma unroll
        for (int ks = 0; ks < 2; ++ks) {
#pragma unroll
            for (int db = 0; db < 4; ++db) {
                int r = db * 16 + l16;
                bf16x8 vf = *(const bf16x8*)&Vs[r * 64 + (((ks * 4 + quad) ^ (r & 7)) * 8)];
#pragma unroll
                for (int mb = 0; mb < 2; ++mb)
                    o[mb][db] = MFMA16(pA[mb][ks], vf, o[mb][db]);
            }
        }
    }

    // epilogue: complete row-sums (reduce over the 4 quads), normalize, store.
    const int b = bh / NH, h = bh % NH;
#pragma unroll
    for (int mb = 0; mb < 2; ++mb) {
        lrow[mb] += __shfl_xor(lrow[mb], 16);
        lrow[mb] += __shfl_xor(lrow[mb], 32);   // now lane holds sum for q=mb*16+l16
        floatx4 inv;
#pragma unroll
        for (int r = 0; r < 4; ++r)
            inv[r] = 1.0f / __shfl(lrow[mb], (lane & 48) | (quad * 4 + r));
#pragma unroll
        for (int db = 0; db < 4; ++db)
#pragma unroll
            for (int r = 0; r < 4; ++r) {
                int l = qw + mb * 16 + quad * 4 + r;
                O[((size_t)b * TL + l) * TD + h * HD + db * 16 + l16] =
                    (bf16)(o[mb][db][r] * inv[r]);
            }
    }
}

// ---------------------------------------------------------------------------
// Output projection: out fp32 = O_bf16 @ Wo + bo. BK=64, XOR swizzle,
// LDS-bounce epilogue aliased onto As/Bs; __launch_bounds__(256,4).
// ---------------------------------------------------------------------------
__global__ __launch_bounds__(256, 4)
void oproj_gemm(const bf16* __restrict__ A, const bf16* __restrict__ Wt,
                const float* __restrict__ bo, float* __restrict__ out)
{
    __shared__ __align__(16) bf16 SM[2 * 128 * 64];   // As | Bs ; epilogue reuses
    bf16* As = SM;
    bf16* Bs = SM + 128 * 64;

    const int t = threadIdx.x;
    const int lane = t & 63, w = t >> 6;
    const int quad = lane >> 4, l16 = lane & 15;
    const int m0 = blockIdx.x * 128;
    const int n0 = blockIdx.y * 128;
    const int rm = (w >> 1) * 64, cn = (w & 1) * 64;

    floatx4 acc[4][4];
#pragma unroll
    for (int i = 0; i < 4; ++i)
#pragma unroll
        for (int j = 0; j < 4; ++j) acc[i][j] = (floatx4){0.f, 0.f, 0.f, 0.f};

    const bf16* gA[4];
    const bf16* gB[4];
#pragma unroll
    for (int i = 0; i < 4; ++i) {
        int n = t + i * 256, r = n >> 3, s = ((n & 7) ^ (r & 7)) * 8;
        gA[i] = A + (size_t)(m0 + r) * TD + s;
        gB[i] = Wt + (size_t)(n0 + r) * TD + s;
    }

    for (int kk = 0; kk < TD; kk += 64) {
#pragma unroll
        for (int i = 0; i < 4; ++i) {
            gl_lds16(gA[i] + kk, As + t * 8 + i * 2048);
            gl_lds16(gB[i] + kk, Bs + t * 8 + i * 2048);
        }
        __syncthreads();
#pragma unroll
        for (int ks = 0; ks < 2; ++ks) {
            bf16x8 af[4], bfr[4];
#pragma unroll
            for (int mb = 0; mb < 4; ++mb) {
                int r = rm + mb * 16 + l16;
                af[mb] = *(const bf16x8*)&As[r * 64 + (((ks * 4 + quad) ^ (r & 7)) * 8)];
            }
#pragma unroll
            for (int nb = 0; nb < 4; ++nb) {
                int r = cn + nb * 16 + l16;
                bfr[nb] = *(const bf16x8*)&Bs[r * 64 + (((ks * 4 + quad) ^ (r & 7)) * 8)];
            }
#pragma unroll
            for (int mb = 0; mb < 4; ++mb)
#pragma unroll
                for (int nb = 0; nb < 4; ++nb)
                    acc[mb][nb] = MFMA16(af[mb], bfr[nb], acc[mb][nb]);
        }
        __syncthreads();
    }

    float bb[4];
#pragma unroll
    for (int nb = 0; nb < 4; ++nb) bb[nb] = bo[n0 + cn + nb * 16 + l16];

    // per-wave f32 bounce aliased onto SM (16*68 floats per wave)
    float* Ew = (float*)SM + w * (16 * 68);
#pragma unroll
    for (int mb = 0; mb < 4; ++mb) {
#pragma unroll
        for (int nb = 0; nb < 4; ++nb)
#pragma unroll
            for (int r = 0; r < 4; ++r)
                Ew[(quad * 4 + r) * 68 + nb * 16 + l16] = acc[mb][nb][r] + bb[nb];
#pragma unroll
        for (int i = 0; i < 4; ++i) {
            int row = i * 4 + (lane >> 4), seg = lane & 15;
            float4 v = *(const float4*)&Ew[row * 68 + seg * 4];
            *(float4*)(out + (size_t)(m0 + rm + mb * 16 + row) * TD + n0 + cn + seg * 4) = v;
        }
    }
}

// ---------------------------------------------------------------------------
extern "C" void kernel_launch(void* const* d_in, const int* in_sizes, int n_in,
                              void* d_out, int out_size, void* d_ws, size_t ws_size,
                              hipStream_t stream)
{
    const float* x  = (const float*)d_in[0];
    const float* Wq = (const float*)d_in[1];
    const float* bq = (const float*)d_in[2];
    const float* Wk = (const float*)d_in[3];
    const float* bk = (const float*)d_in[4];
    const float* Wv = (const float*)d_in[5];
    const float* bv = (const float*)d_in[6];
    const float* Wo = (const float*)d_in[7];
    const float* bo = (const float*)d_in[8];

    const size_t NXE = (size_t)MTOT * TD;    // 6,291,456
    const size_t NWE = (size_t)TD * TD;      // 589,824

    bf16* xb  = (bf16*)d_ws;
    bf16* Wqt = xb + NXE;
    bf16* Wkt = Wqt + NWE;
    bf16* Wvt = Wkt + NWE;
    bf16* Wot = Wvt + NWE;
    bf16* Qb  = Wot + NWE;
    bf16* Kb  = Qb + NXE;
    bf16* Vtb = Kb + NXE;
    bf16* Ob  = Vtb + NXE;

    prep_kernel<<<6144 + 576, 256, 0, stream>>>(x, xb, Wq, Wk, Wv, Wo,
                                                Wqt, Wkt, Wvt, Wot);
    qkv_gemm<<<dim3(MTOT / 128, TD / 128, 3), 256, 0, stream>>>(
        xb, Wqt, Wkt, Wvt, bq, bk, bv, Qb, Kb, Vtb);
    attn_kernel<<<dim3(TL / 128, NB * NH), 256, 0, stream>>>(Qb, Kb, Vtb, Ob);
    oproj_gemm<<<dim3(MTOT / 128, TD / 128), 256, 0, stream>>>(Ob, Wot, bo,
                                                               (float*)d_out);
}

// Round 5
// 217.847 us; speedup vs baseline: 1.1395x; 1.1395x over previous
//
#include <hip/hip_runtime.h>
#include <math.h>

#define TL 2048
#define TD 768
#define NH 12
#define HD 64
#define NB 4
#define MTOT (NB * TL)   // 8192

typedef __bf16 bf16;
typedef __attribute__((ext_vector_type(4))) __bf16 bf16x4;
typedef __attribute__((ext_vector_type(8))) __bf16 bf16x8;
typedef __attribute__((ext_vector_type(4))) float floatx4;

// Q pre-scale: 1/sqrt(64) * log2(e)  (softmax computed in exp2 domain)
#define QSCALE 0.18033688011112042f

#define MFMA16(A, B, C) __builtin_amdgcn_mfma_f32_16x16x32_bf16(A, B, C, 0, 0, 0)

__device__ __forceinline__ void gl_lds16(const void* g, void* l) {
    __builtin_amdgcn_global_load_lds(
        (const __attribute__((address_space(1))) void*)g,
        (__attribute__((address_space(3))) void*)l, 16, 0, 0);
}

__device__ __forceinline__ floatx4 exp2x4(floatx4 a) {
    floatx4 r;
    r.x = __builtin_amdgcn_exp2f(a.x);
    r.y = __builtin_amdgcn_exp2f(a.y);
    r.z = __builtin_amdgcn_exp2f(a.z);
    r.w = __builtin_amdgcn_exp2f(a.w);
    return r;
}

// Inverse of the key->LDS-row permutation that makes QK^T's C-registers
// coincide with PV's A-fragment layout. Row r holds key kperm_inv(r).
//   row bits [k5 k2 k4 k3 k1 k0] -> key
__device__ __forceinline__ int kperm_inv(int r) {
    return (r & 35) | (((r >> 2) & 3) << 3) | (((r >> 4) & 1) << 2);
}

// ---------------------------------------------------------------------------
// prep: fused x fp32->bf16 cast (blocks 0..6143) + W transpose->bf16
// (blocks 6144..6719). One launch instead of two.
// ---------------------------------------------------------------------------
__global__ __launch_bounds__(256)
void prep_kernel(const float* __restrict__ x, bf16* __restrict__ xb,
                 const float* __restrict__ W0, const float* __restrict__ W1,
                 const float* __restrict__ W2, const float* __restrict__ W3,
                 bf16* __restrict__ T0, bf16* __restrict__ T1,
                 bf16* __restrict__ T2, bf16* __restrict__ T3)
{
    __shared__ float Ts[64][65];
    const int t = threadIdx.x;

    if (blockIdx.x < 6144) {
        size_t i = ((size_t)blockIdx.x * 256 + t) * 4;
        float4 v = *(const float4*)(x + i);
        bf16x4 o;
        o[0] = (bf16)v.x; o[1] = (bf16)v.y; o[2] = (bf16)v.z; o[3] = (bf16)v.w;
        *(bf16x4*)(xb + i) = o;
        return;
    }

    const int bid = blockIdx.x - 6144;          // 0..575
    const int z = bid / 144, rem = bid % 144;
    const float* W = z == 0 ? W0 : z == 1 ? W1 : z == 2 ? W2 : W3;
    bf16*       T = z == 0 ? T0 : z == 1 ? T1 : z == 2 ? T2 : T3;
    const int k0 = (rem % 12) * 64, n0 = (rem / 12) * 64;
    const int rr = t >> 4, cc = (t & 15) * 4;
#pragma unroll
    for (int i = 0; i < 4; ++i) {
        int row = rr + i * 16;
        float4 v = *(const float4*)(W + (size_t)(k0 + row) * TD + n0 + cc);
        Ts[row][cc] = v.x; Ts[row][cc + 1] = v.y;
        Ts[row][cc + 2] = v.z; Ts[row][cc + 3] = v.w;
    }
    __syncthreads();
#pragma unroll
    for (int i = 0; i < 4; ++i) {
        int n = rr + i * 16;
        bf16x4 pk;
#pragma unroll
        for (int j = 0; j < 4; ++j) pk[j] = (bf16)Ts[cc + j][n];
        *(bf16x4*)(T + (size_t)(n0 + n) * TD + k0 + cc) = pk;
    }
}

// ---------------------------------------------------------------------------
// QKV GEMM: 128x128 tile, BK=64 (12 K-iters), XOR-swizzled LDS (no pad),
// global_load_lds staging, LDS-bounce coalesced epilogue.
// Epilogue bounce ALIASED onto As (safe after the final barrier) -> LDS
// 32 KB. Natural register allocation (no min-waves cap; round-4's (256,4)
// forced VGPR=64 and spilled the accumulator -> 74us; do not reintroduce).
// Q,K -> [bh][l][64] bf16 (Q pre-scaled by QSCALE); V -> [bh][d][2048] bf16.
// ---------------------------------------------------------------------------
__global__ __launch_bounds__(256)
void qkv_gemm(const bf16* __restrict__ xb,
              const bf16* __restrict__ Wqt, const bf16* __restrict__ Wkt,
              const bf16* __restrict__ Wvt,
              const float* __restrict__ bq, const float* __restrict__ bk,
              const float* __restrict__ bv,
              bf16* __restrict__ Q, bf16* __restrict__ K, bf16* __restrict__ Vt)
{
    __shared__ __align__(16) bf16 SM[2 * 128 * 64];   // As | Bs ; epilogue reuses
    bf16* As = SM;
    bf16* Bs = SM + 128 * 64;

    const int t = threadIdx.x;
    const int lane = t & 63, w = t >> 6;
    const int quad = lane >> 4, l16 = lane & 15;
    const int m0 = blockIdx.x * 128;
    const int n0 = blockIdx.y * 128;
    const int which = blockIdx.z;
    const bf16*  W    = which == 0 ? Wqt : which == 1 ? Wkt : Wvt;
    const float* bias = which == 0 ? bq  : which == 1 ? bk  : bv;
    const float scale = which == 0 ? QSCALE : 1.0f;

    const int rm = (w >> 1) * 64, cn = (w & 1) * 64;

    floatx4 acc[4][4];
#pragma unroll
    for (int i = 0; i < 4; ++i)
#pragma unroll
        for (int j = 0; j < 4; ++j) acc[i][j] = (floatx4){0.f, 0.f, 0.f, 0.f};

    // staging sources: slot n = t + i*256; row = n>>3; seg = (n&7)^(row&7)
    const bf16* gA[4];
    const bf16* gB[4];
#pragma unroll
    for (int i = 0; i < 4; ++i) {
        int n = t + i * 256, r = n >> 3, s = ((n & 7) ^ (r & 7)) * 8;
        gA[i] = xb + (size_t)(m0 + r) * TD + s;
        gB[i] = W + (size_t)(n0 + r) * TD + s;
    }

    for (int kk = 0; kk < TD; kk += 64) {
#pragma unroll
        for (int i = 0; i < 4; ++i) {
            gl_lds16(gA[i] + kk, As + t * 8 + i * 2048);
            gl_lds16(gB[i] + kk, Bs + t * 8 + i * 2048);
        }
        __syncthreads();
#pragma unroll
        for (int ks = 0; ks < 2; ++ks) {
            bf16x8 af[4], bfr[4];
#pragma unroll
            for (int mb = 0; mb < 4; ++mb) {
                int r = rm + mb * 16 + l16;
                af[mb] = *(const bf16x8*)&As[r * 64 + (((ks * 4 + quad) ^ (r & 7)) * 8)];
            }
#pragma unroll
            for (int nb = 0; nb < 4; ++nb) {
                int r = cn + nb * 16 + l16;
                bfr[nb] = *(const bf16x8*)&Bs[r * 64 + (((ks * 4 + quad) ^ (r & 7)) * 8)];
            }
#pragma unroll
            for (int mb = 0; mb < 4; ++mb)
#pragma unroll
                for (int nb = 0; nb < 4; ++nb)
                    acc[mb][nb] = MFMA16(af[mb], bfr[nb], acc[mb][nb]);
        }
        __syncthreads();
    }

    float bsc[4];
#pragma unroll
    for (int nb = 0; nb < 4; ++nb)
        bsc[nb] = bias[n0 + cn + nb * 16 + l16] * scale;

    const int token0 = m0 + rm;
    const int b  = token0 >> 11;
    const int l0 = token0 & (TL - 1);
    const int h  = (n0 + cn) >> 6;
    const int bh = b * NH + h;
    // per-wave epilogue bounce region aliased onto SM (all LDS reads of the
    // K-loop completed before the final barrier above; regions are
    // wave-private so no further barrier is needed)
    bf16* Ew = SM + w * (16 * 72);

    if (which < 2) {
        bf16* gp = (which == 0 ? Q : K) + ((size_t)bh * TL + l0) * HD;
#pragma unroll
        for (int mb = 0; mb < 4; ++mb) {
#pragma unroll
            for (int nb = 0; nb < 4; ++nb)
#pragma unroll
                for (int r = 0; r < 4; ++r)
                    Ew[(quad * 4 + r) * 72 + nb * 16 + l16] =
                        (bf16)(acc[mb][nb][r] * scale + bsc[nb]);
#pragma unroll
            for (int i = 0; i < 2; ++i) {
                int row = i * 8 + (lane >> 3), seg = lane & 7;
                bf16x8 v = *(const bf16x8*)&Ew[row * 72 + seg * 8];
                *(bf16x8*)(gp + (size_t)(mb * 16 + row) * HD + seg * 8) = v;
            }
        }
    } else {
#pragma unroll
        for (int nb = 0; nb < 4; ++nb) {
#pragma unroll
            for (int mb = 0; mb < 4; ++mb) {
                bf16x4 pk;
#pragma unroll
                for (int r = 0; r < 4; ++r) pk[r] = (bf16)(acc[mb][nb][r] + bsc[nb]);
                *(bf16x4*)&Ew[l16 * 72 + mb * 16 + quad * 4] = pk;
            }
#pragma unroll
            for (int i = 0; i < 2; ++i) {
                int row = i * 8 + (lane >> 3), seg = lane & 7;
                bf16x8 v = *(const bf16x8*)&Ew[row * 72 + seg * 8];
                *(bf16x8*)(Vt + ((size_t)bh * HD + nb * 16 + row) * TL + l0 + seg * 8) = v;
            }
        }
    }
}

// ---------------------------------------------------------------------------
// MFMA flash attention v5 (round-0 exact): P never touches LDS; K/V staged
// via global_load_lds with the key permutation folded into the per-lane
// global source address and XOR segment swizzle instead of padding.
// ---------------------------------------------------------------------------
__global__ __launch_bounds__(256)
void attn_kernel(const bf16* __restrict__ Q, const bf16* __restrict__ K,
                 const bf16* __restrict__ Vt, bf16* __restrict__ O)
{
    __shared__ __align__(16) bf16 Ks[64 * 64];   // [kperm(key)][seg^(row&7)]
    __shared__ __align__(16) bf16 Vs[64 * 64];   // [d][seg^(d&7)] over keys

    const int t = threadIdx.x;
    const int lane = t & 63, w = t >> 6;
    const int quad = lane >> 4, l16 = lane & 15;

    // XCD-aware swizzle: blocks on the same XCD (n%8) share one bh's K/V
    const int n = blockIdx.y * gridDim.x + blockIdx.x;   // 0..767
    const int xcd = n & 7, s = n >> 3;                   // s: 0..95
    const int bh = xcd * 6 + (s >> 4);
    const int q0 = (s & 15) * 128;

    const bf16* Qb = Q + (size_t)bh * TL * HD;
    const bf16* Kb = K + (size_t)bh * TL * HD;
    const bf16* Vb = Vt + (size_t)bh * HD * TL;

    const int qw = q0 + w * 32;
    bf16x8 qf[2][2];
#pragma unroll
    for (int mb = 0; mb < 2; ++mb)
#pragma unroll
        for (int ks = 0; ks < 2; ++ks)
            qf[mb][ks] = *(const bf16x8*)(Qb + (size_t)(qw + mb * 16 + l16) * HD
                                          + ks * 32 + quad * 8);

    float lrow[2] = {0.f, 0.f};      // per-lane partial row-sum for q = mb*16+l16
    floatx4 o[2][4];
#pragma unroll
    for (int mb = 0; mb < 2; ++mb)
#pragma unroll
        for (int db = 0; db < 4; ++db) o[mb][db] = (floatx4){0.f, 0.f, 0.f, 0.f};

    // staging sources: slots n = t (i=0), t+256 (i=1); row = n>>3, 8 slots/row
    const bf16* gK[2];
    const bf16* gV[2];
#pragma unroll
    for (int i = 0; i < 2; ++i) {
        int nn = t + i * 256, r = nn >> 3, sg = ((nn & 7) ^ (r & 7)) * 8;
        gK[i] = Kb + (size_t)kperm_inv(r) * HD + sg;   // + k0*HD per step
        gV[i] = Vb + (size_t)r * TL + sg;              // + k0 per step
    }

    for (int kt = 0; kt < TL / 64; ++kt) {
        const int k0 = kt * 64;
        __syncthreads();
#pragma unroll
        for (int i = 0; i < 2; ++i) {
            gl_lds16(gK[i] + (size_t)k0 * HD, Ks + t * 8 + i * 2048);
            gl_lds16(gV[i] + k0,              Vs + t * 8 + i * 2048);
        }
        __syncthreads();

        // S^T = K' Q^T : lane holds S[q=mb*16+l16][key=32(nb>>1)+4(nb&1)+8quad+r]
        floatx4 s2[2][4];
#pragma unroll
        for (int nb = 0; nb < 4; ++nb) {
            int r = nb * 16 + l16;
            bf16x8 kf0 = *(const bf16x8*)&Ks[r * 64 + ((quad ^ (r & 7)) * 8)];
            bf16x8 kf1 = *(const bf16x8*)&Ks[r * 64 + (((4 + quad) ^ (r & 7)) * 8)];
#pragma unroll
            for (int mb = 0; mb < 2; ++mb) {
                floatx4 a = (floatx4){0.f, 0.f, 0.f, 0.f};
                a = MFMA16(kf0, qf[mb][0], a);
                a = MFMA16(kf1, qf[mb][1], a);
                s2[mb][nb] = a;
            }
        }

        // P = 2^S in-register; repack into PV A-fragments (keys ks*32+8quad+j)
        bf16x8 pA[2][2];
#pragma unroll
        for (int mb = 0; mb < 2; ++mb) {
#pragma unroll
            for (int ks = 0; ks < 2; ++ks) {
                floatx4 p0 = exp2x4(s2[mb][2 * ks]);
                floatx4 p1 = exp2x4(s2[mb][2 * ks + 1]);
                lrow[mb] += (p0.x + p0.y + p0.z + p0.w) + (p1.x + p1.y + p1.z + p1.w);
                bf16x8 pk;
                pk[0] = (bf16)p0.x; pk[1] = (bf16)p0.y; pk[2] = (bf16)p0.z; pk[3] = (bf16)p0.w;
                pk[4] = (bf16)p1.x; pk[5] = (bf16)p1.y; pk[6] = (bf16)p1.z; pk[7] = (bf16)p1.w;
                pA[mb][ks] = pk;
            }
        }

        // O += P V
#pragma unroll
        for (int ks = 0; ks < 2; ++ks) {
#pragma unroll
            for (int db = 0; db < 4; ++db) {
                int r = db * 16 + l16;
                bf16x8 vf = *(const bf16x8*)&Vs[r * 64 + (((ks * 4 + quad) ^ (r & 7)) * 8)];
#pragma unroll
                for (int mb = 0; mb < 2; ++mb)
                    o[mb][db] = MFMA16(pA[mb][ks], vf, o[mb][db]);
            }
        }
    }

    // epilogue: complete row-sums (reduce over the 4 quads), normalize, store.
    const int b = bh / NH, h = bh % NH;
#pragma unroll
    for (int mb = 0; mb < 2; ++mb) {
        lrow[mb] += __shfl_xor(lrow[mb], 16);
        lrow[mb] += __shfl_xor(lrow[mb], 32);   // now lane holds sum for q=mb*16+l16
        floatx4 inv;
#pragma unroll
        for (int r = 0; r < 4; ++r)
            inv[r] = 1.0f / __shfl(lrow[mb], (lane & 48) | (quad * 4 + r));
#pragma unroll
        for (int db = 0; db < 4; ++db)
#pragma unroll
            for (int r = 0; r < 4; ++r) {
                int l = qw + mb * 16 + quad * 4 + r;
                O[((size_t)b * TL + l) * TD + h * HD + db * 16 + l16] =
                    (bf16)(o[mb][db][r] * inv[r]);
            }
    }
}

// ---------------------------------------------------------------------------
// Output projection: out fp32 = O_bf16 @ Wo + bo. BK=64, XOR swizzle,
// LDS-bounce epilogue aliased onto As/Bs; natural register allocation.
// ---------------------------------------------------------------------------
__global__ __launch_bounds__(256)
void oproj_gemm(const bf16* __restrict__ A, const bf16* __restrict__ Wt,
                const float* __restrict__ bo, float* __restrict__ out)
{
    __shared__ __align__(16) bf16 SM[2 * 128 * 64];   // As | Bs ; epilogue reuses
    bf16* As = SM;
    bf16* Bs = SM + 128 * 64;

    const int t = threadIdx.x;
    const int lane = t & 63, w = t >> 6;
    const int quad = lane >> 4, l16 = lane & 15;
    const int m0 = blockIdx.x * 128;
    const int n0 = blockIdx.y * 128;
    const int rm = (w >> 1) * 64, cn = (w & 1) * 64;

    floatx4 acc[4][4];
#pragma unroll
    for (int i = 0; i < 4; ++i)
#pragma unroll
        for (int j = 0; j < 4; ++j) acc[i][j] = (floatx4){0.f, 0.f, 0.f, 0.f};

    const bf16* gA[4];
    const bf16* gB[4];
#pragma unroll
    for (int i = 0; i < 4; ++i) {
        int n = t + i * 256, r = n >> 3, s = ((n & 7) ^ (r & 7)) * 8;
        gA[i] = A + (size_t)(m0 + r) * TD + s;
        gB[i] = Wt + (size_t)(n0 + r) * TD + s;
    }

    for (int kk = 0; kk < TD; kk += 64) {
#pragma unroll
        for (int i = 0; i < 4; ++i) {
            gl_lds16(gA[i] + kk, As + t * 8 + i * 2048);
            gl_lds16(gB[i] + kk, Bs + t * 8 + i * 2048);
        }
        __syncthreads();
#pragma unroll
        for (int ks = 0; ks < 2; ++ks) {
            bf16x8 af[4], bfr[4];
#pragma unroll
            for (int mb = 0; mb < 4; ++mb) {
                int r = rm + mb * 16 + l16;
                af[mb] = *(const bf16x8*)&As[r * 64 + (((ks * 4 + quad) ^ (r & 7)) * 8)];
            }
#pragma unroll
            for (int nb = 0; nb < 4; ++nb) {
                int r = cn + nb * 16 + l16;
                bfr[nb] = *(const bf16x8*)&Bs[r * 64 + (((ks * 4 + quad) ^ (r & 7)) * 8)];
            }
#pragma unroll
            for (int mb = 0; mb < 4; ++mb)
#pragma unroll
                for (int nb = 0; nb < 4; ++nb)
                    acc[mb][nb] = MFMA16(af[mb], bfr[nb], acc[mb][nb]);
        }
        __syncthreads();
    }

    float bb[4];
#pragma unroll
    for (int nb = 0; nb < 4; ++nb) bb[nb] = bo[n0 + cn + nb * 16 + l16];

    // per-wave f32 bounce aliased onto SM (16*68 floats per wave)
    float* Ew = (float*)SM + w * (16 * 68);
#pragma unroll
    for (int mb = 0; mb < 4; ++mb) {
#pragma unroll
        for (int nb = 0; nb < 4; ++nb)
#pragma unroll
            for (int r = 0; r < 4; ++r)
                Ew[(quad * 4 + r) * 68 + nb * 16 + l16] = acc[mb][nb][r] + bb[nb];
#pragma unroll
        for (int i = 0; i < 4; ++i) {
            int row = i * 4 + (lane >> 4), seg = lane & 15;
            float4 v = *(const float4*)&Ew[row * 68 + seg * 4];
            *(float4*)(out + (size_t)(m0 + rm + mb * 16 + row) * TD + n0 + cn + seg * 4) = v;
        }
    }
}

// ---------------------------------------------------------------------------
extern "C" void kernel_launch(void* const* d_in, const int* in_sizes, int n_in,
                              void* d_out, int out_size, void* d_ws, size_t ws_size,
                              hipStream_t stream)
{
    const float* x  = (const float*)d_in[0];
    const float* Wq = (const float*)d_in[1];
    const float* bq = (const float*)d_in[2];
    const float* Wk = (const float*)d_in[3];
    const float* bk = (const float*)d_in[4];
    const float* Wv = (const float*)d_in[5];
    const float* bv = (const float*)d_in[6];
    const float* Wo = (const float*)d_in[7];
    const float* bo = (const float*)d_in[8];

    const size_t NXE = (size_t)MTOT * TD;    // 6,291,456
    const size_t NWE = (size_t)TD * TD;      // 589,824

    bf16* xb  = (bf16*)d_ws;
    bf16* Wqt = xb + NXE;
    bf16* Wkt = Wqt + NWE;
    bf16* Wvt = Wkt + NWE;
    bf16* Wot = Wvt + NWE;
    bf16* Qb  = Wot + NWE;
    bf16* Kb  = Qb + NXE;
    bf16* Vtb = Kb + NXE;
    bf16* Ob  = Vtb + NXE;

    prep_kernel<<<6144 + 576, 256, 0, stream>>>(x, xb, Wq, Wk, Wv, Wo,
                                                Wqt, Wkt, Wvt, Wot);
    qkv_gemm<<<dim3(MTOT / 128, TD / 128, 3), 256, 0, stream>>>(
        xb, Wqt, Wkt, Wvt, bq, bk, bv, Qb, Kb, Vtb);
    attn_kernel<<<dim3(TL / 128, NB * NH), 256, 0, stream>>>(Qb, Kb, Vtb, Ob);
    oproj_gemm<<<dim3(MTOT / 128, TD / 128), 256, 0, stream>>>(Ob, Wot, bo,
                                                               (float*)d_out);
}

// Round 7
// 216.047 us; speedup vs baseline: 1.1490x; 1.0083x over previous
//
#include <hip/hip_runtime.h>
#include <hip/hip_cooperative_groups.h>
#include <math.h>

namespace cg = cooperative_groups;

#define TL 2048
#define TD 768
#define NH 12
#define HD 64
#define NB 4
#define MTOT (NB * TL)   // 8192

typedef __bf16 bf16;
typedef __attribute__((ext_vector_type(4))) __bf16 bf16x4;
typedef __attribute__((ext_vector_type(8))) __bf16 bf16x8;
typedef __attribute__((ext_vector_type(4))) float floatx4;

// Q pre-scale: 1/sqrt(64) * log2(e)  (softmax computed in exp2 domain)
#define QSCALE 0.18033688011112042f

#define MFMA16(A, B, C) __builtin_amdgcn_mfma_f32_16x16x32_bf16(A, B, C, 0, 0, 0)

__device__ __forceinline__ void gl_lds16(const void* g, void* l) {
    __builtin_amdgcn_global_load_lds(
        (const __attribute__((address_space(1))) void*)g,
        (__attribute__((address_space(3))) void*)l, 16, 0, 0);
}

__device__ __forceinline__ floatx4 exp2x4(floatx4 a) {
    floatx4 r;
    r.x = __builtin_amdgcn_exp2f(a.x);
    r.y = __builtin_amdgcn_exp2f(a.y);
    r.z = __builtin_amdgcn_exp2f(a.z);
    r.w = __builtin_amdgcn_exp2f(a.w);
    return r;
}

// Inverse of the key->LDS-row permutation that makes QK^T's C-registers
// coincide with PV's A-fragment layout. Row r holds key kperm_inv(r).
__device__ __forceinline__ int kperm_inv(int r) {
    return (r & 35) | (((r >> 2) & 3) << 3) | (((r >> 4) & 1) << 2);
}

// ===========================================================================
// Shared device-function phase bodies
// ===========================================================================

// Flash attention tile (verified R0/R5 body). smem needs 16384 B.
__device__ __forceinline__ void attn_phase(
    char* smem, int n,
    const bf16* __restrict__ Q, const bf16* __restrict__ K,
    const bf16* __restrict__ Vt, bf16* __restrict__ O)
{
    bf16* Ks = (bf16*)smem;        // [kperm(key)][seg^(row&7)]
    bf16* Vs = Ks + 64 * 64;       // [d][seg^(d&7)] over keys

    const int t = threadIdx.x;
    const int lane = t & 63, w = t >> 6;
    const int quad = lane >> 4, l16 = lane & 15;

    const int xcd = n & 7, s = n >> 3;
    const int bh = xcd * 6 + (s >> 4);
    const int q0 = (s & 15) * 128;

    const bf16* Qb = Q + (size_t)bh * TL * HD;
    const bf16* Kb = K + (size_t)bh * TL * HD;
    const bf16* Vb = Vt + (size_t)bh * HD * TL;

    const int qw = q0 + w * 32;
    bf16x8 qf[2][2];
#pragma unroll
    for (int mb = 0; mb < 2; ++mb)
#pragma unroll
        for (int ks = 0; ks < 2; ++ks)
            qf[mb][ks] = *(const bf16x8*)(Qb + (size_t)(qw + mb * 16 + l16) * HD
                                          + ks * 32 + quad * 8);

    float lrow[2] = {0.f, 0.f};
    floatx4 o[2][4];
#pragma unroll
    for (int mb = 0; mb < 2; ++mb)
#pragma unroll
        for (int db = 0; db < 4; ++db) o[mb][db] = (floatx4){0.f, 0.f, 0.f, 0.f};

    const bf16* gK[2];
    const bf16* gV[2];
#pragma unroll
    for (int i = 0; i < 2; ++i) {
        int nn = t + i * 256, r = nn >> 3, sg = ((nn & 7) ^ (r & 7)) * 8;
        gK[i] = Kb + (size_t)kperm_inv(r) * HD + sg;
        gV[i] = Vb + (size_t)r * TL + sg;
    }

    for (int kt = 0; kt < TL / 64; ++kt) {
        const int k0 = kt * 64;
        __syncthreads();
#pragma unroll
        for (int i = 0; i < 2; ++i) {
            gl_lds16(gK[i] + (size_t)k0 * HD, Ks + t * 8 + i * 2048);
            gl_lds16(gV[i] + k0,              Vs + t * 8 + i * 2048);
        }
        __syncthreads();

        floatx4 s2[2][4];
#pragma unroll
        for (int nb = 0; nb < 4; ++nb) {
            int r = nb * 16 + l16;
            bf16x8 kf0 = *(const bf16x8*)&Ks[r * 64 + ((quad ^ (r & 7)) * 8)];
            bf16x8 kf1 = *(const bf16x8*)&Ks[r * 64 + (((4 + quad) ^ (r & 7)) * 8)];
#pragma unroll
            for (int mb = 0; mb < 2; ++mb) {
                floatx4 a = (floatx4){0.f, 0.f, 0.f, 0.f};
                a = MFMA16(kf0, qf[mb][0], a);
                a = MFMA16(kf1, qf[mb][1], a);
                s2[mb][nb] = a;
            }
        }

        bf16x8 pA[2][2];
#pragma unroll
        for (int mb = 0; mb < 2; ++mb) {
#pragma unroll
            for (int ks = 0; ks < 2; ++ks) {
                floatx4 p0 = exp2x4(s2[mb][2 * ks]);
                floatx4 p1 = exp2x4(s2[mb][2 * ks + 1]);
                lrow[mb] += (p0.x + p0.y + p0.z + p0.w) + (p1.x + p1.y + p1.z + p1.w);
                bf16x8 pk;
                pk[0] = (bf16)p0.x; pk[1] = (bf16)p0.y; pk[2] = (bf16)p0.z; pk[3] = (bf16)p0.w;
                pk[4] = (bf16)p1.x; pk[5] = (bf16)p1.y; pk[6] = (bf16)p1.z; pk[7] = (bf16)p1.w;
                pA[mb][ks] = pk;
            }
        }

#pragma unroll
        for (int ks = 0; ks < 2; ++ks) {
#pragma unroll
            for (int db = 0; db < 4; ++db) {
                int r = db * 16 + l16;
                bf16x8 vf = *(const bf16x8*)&Vs[r * 64 + (((ks * 4 + quad) ^ (r & 7)) * 8)];
#pragma unroll
                for (int mb = 0; mb < 2; ++mb)
                    o[mb][db] = MFMA16(pA[mb][ks], vf, o[mb][db]);
            }
        }
    }

    const int b = bh / NH, h = bh % NH;
#pragma unroll
    for (int mb = 0; mb < 2; ++mb) {
        lrow[mb] += __shfl_xor(lrow[mb], 16);
        lrow[mb] += __shfl_xor(lrow[mb], 32);
        floatx4 inv;
#pragma unroll
        for (int r = 0; r < 4; ++r)
            inv[r] = 1.0f / __shfl(lrow[mb], (lane & 48) | (quad * 4 + r));
#pragma unroll
        for (int db = 0; db < 4; ++db)
#pragma unroll
            for (int r = 0; r < 4; ++r) {
                int l = qw + mb * 16 + quad * 4 + r;
                O[((size_t)b * TL + l) * TD + h * HD + db * 16 + l16] =
                    (bf16)(o[mb][db][r] * inv[r]);
            }
    }
}

// One 128x128 QKV tile, BK=32 (16 KB LDS; mega-kernel budget). Row-swizzle
// key sw(r) = (r ^ (r>>2)) & 3 keeps ds_read_b128 at <=2-way conflicts.
__device__ __forceinline__ void qkv_tile32(
    char* smem, int m0, int n0, int which,
    const bf16* __restrict__ xb,
    const bf16* __restrict__ Wqt, const bf16* __restrict__ Wkt,
    const bf16* __restrict__ Wvt,
    const float* __restrict__ bq, const float* __restrict__ bk,
    const float* __restrict__ bv,
    bf16* __restrict__ Q, bf16* __restrict__ K, bf16* __restrict__ Vt)
{
    bf16* As = (bf16*)smem;          // 128x32 swizzled (8 KB)
    bf16* Bs = As + 128 * 32;        // 8 KB

    const int t = threadIdx.x;
    const int lane = t & 63, w = t >> 6;
    const int quad = lane >> 4, l16 = lane & 15;
    const bf16*  W    = which == 0 ? Wqt : which == 1 ? Wkt : Wvt;
    const float* bias = which == 0 ? bq  : which == 1 ? bk  : bv;
    const float scale = which == 0 ? QSCALE : 1.0f;
    const int rm = (w >> 1) * 64, cn = (w & 1) * 64;

    floatx4 acc[4][4];
#pragma unroll
    for (int i = 0; i < 4; ++i)
#pragma unroll
        for (int j = 0; j < 4; ++j) acc[i][j] = (floatx4){0.f, 0.f, 0.f, 0.f};

    const bf16* gA[2];
    const bf16* gB[2];
#pragma unroll
    for (int i = 0; i < 2; ++i) {
        int nn = t + i * 256, r = nn >> 2;
        int sg = (((nn & 3) ^ ((r ^ (r >> 2)) & 3))) * 8;
        gA[i] = xb + (size_t)(m0 + r) * TD + sg;
        gB[i] = W + (size_t)(n0 + r) * TD + sg;
    }

    __syncthreads();   // previous tile's epilogue-LDS reads complete

    for (int kk = 0; kk < TD; kk += 32) {
#pragma unroll
        for (int i = 0; i < 2; ++i) {
            gl_lds16(gA[i] + kk, As + t * 8 + i * 2048);
            gl_lds16(gB[i] + kk, Bs + t * 8 + i * 2048);
        }
        __syncthreads();
        bf16x8 af[4], bfr[4];
#pragma unroll
        for (int mb = 0; mb < 4; ++mb) {
            int r = rm + mb * 16 + l16;
            af[mb] = *(const bf16x8*)&As[r * 32 + ((quad ^ ((r ^ (r >> 2)) & 3)) * 8)];
        }
#pragma unroll
        for (int nb = 0; nb < 4; ++nb) {
            int r = cn + nb * 16 + l16;
            bfr[nb] = *(const bf16x8*)&Bs[r * 32 + ((quad ^ ((r ^ (r >> 2)) & 3)) * 8)];
        }
#pragma unroll
        for (int mb = 0; mb < 4; ++mb)
#pragma unroll
            for (int nb = 0; nb < 4; ++nb)
                acc[mb][nb] = MFMA16(af[mb], bfr[nb], acc[mb][nb]);
        __syncthreads();
    }

    float bsc[4];
#pragma unroll
    for (int nb = 0; nb < 4; ++nb)
        bsc[nb] = bias[n0 + cn + nb * 16 + l16] * scale;

    const int token0 = m0 + rm;
    const int b  = token0 >> 11;
    const int l0 = token0 & (TL - 1);
    const int h  = (n0 + cn) >> 6;
    const int bh = b * NH + h;
    bf16* Ew = (bf16*)smem + w * (16 * 72);   // wave-private bounce

    if (which < 2) {
        bf16* gp = (which == 0 ? Q : K) + ((size_t)bh * TL + l0) * HD;
#pragma unroll
        for (int mb = 0; mb < 4; ++mb) {
#pragma unroll
            for (int nb = 0; nb < 4; ++nb)
#pragma unroll
                for (int r = 0; r < 4; ++r)
                    Ew[(quad * 4 + r) * 72 + nb * 16 + l16] =
                        (bf16)(acc[mb][nb][r] * scale + bsc[nb]);
#pragma unroll
            for (int i = 0; i < 2; ++i) {
                int row = i * 8 + (lane >> 3), seg = lane & 7;
                bf16x8 v = *(const bf16x8*)&Ew[row * 72 + seg * 8];
                *(bf16x8*)(gp + (size_t)(mb * 16 + row) * HD + seg * 8) = v;
            }
        }
    } else {
#pragma unroll
        for (int nb = 0; nb < 4; ++nb) {
#pragma unroll
            for (int mb = 0; mb < 4; ++mb) {
                bf16x4 pk;
#pragma unroll
                for (int r = 0; r < 4; ++r) pk[r] = (bf16)(acc[mb][nb][r] + bsc[nb]);
                *(bf16x4*)&Ew[l16 * 72 + mb * 16 + quad * 4] = pk;
            }
#pragma unroll
            for (int i = 0; i < 2; ++i) {
                int row = i * 8 + (lane >> 3), seg = lane & 7;
                bf16x8 v = *(const bf16x8*)&Ew[row * 72 + seg * 8];
                *(bf16x8*)(Vt + ((size_t)bh * HD + nb * 16 + row) * TL + l0 + seg * 8) = v;
            }
        }
    }
}

// One 128x128 oproj tile, BK=32; f32 epilogue bounce (17408 B) aliased on smem.
__device__ __forceinline__ void oproj_tile32(
    char* smem, int m0, int n0,
    const bf16* __restrict__ A, const bf16* __restrict__ Wt,
    const float* __restrict__ bo, float* __restrict__ out)
{
    bf16* As = (bf16*)smem;
    bf16* Bs = As + 128 * 32;

    const int t = threadIdx.x;
    const int lane = t & 63, w = t >> 6;
    const int quad = lane >> 4, l16 = lane & 15;
    const int rm = (w >> 1) * 64, cn = (w & 1) * 64;

    floatx4 acc[4][4];
#pragma unroll
    for (int i = 0; i < 4; ++i)
#pragma unroll
        for (int j = 0; j < 4; ++j) acc[i][j] = (floatx4){0.f, 0.f, 0.f, 0.f};

    const bf16* gA[2];
    const bf16* gB[2];
#pragma unroll
    for (int i = 0; i < 2; ++i) {
        int nn = t + i * 256, r = nn >> 2;
        int sg = (((nn & 3) ^ ((r ^ (r >> 2)) & 3))) * 8;
        gA[i] = A + (size_t)(m0 + r) * TD + sg;
        gB[i] = Wt + (size_t)(n0 + r) * TD + sg;
    }

    for (int kk = 0; kk < TD; kk += 32) {
#pragma unroll
        for (int i = 0; i < 2; ++i) {
            gl_lds16(gA[i] + kk, As + t * 8 + i * 2048);
            gl_lds16(gB[i] + kk, Bs + t * 8 + i * 2048);
        }
        __syncthreads();
        bf16x8 af[4], bfr[4];
#pragma unroll
        for (int mb = 0; mb < 4; ++mb) {
            int r = rm + mb * 16 + l16;
            af[mb] = *(const bf16x8*)&As[r * 32 + ((quad ^ ((r ^ (r >> 2)) & 3)) * 8)];
        }
#pragma unroll
        for (int nb = 0; nb < 4; ++nb) {
            int r = cn + nb * 16 + l16;
            bfr[nb] = *(const bf16x8*)&Bs[r * 32 + ((quad ^ ((r ^ (r >> 2)) & 3)) * 8)];
        }
#pragma unroll
        for (int mb = 0; mb < 4; ++mb)
#pragma unroll
            for (int nb = 0; nb < 4; ++nb)
                acc[mb][nb] = MFMA16(af[mb], bfr[nb], acc[mb][nb]);
        __syncthreads();
    }

    float bb[4];
#pragma unroll
    for (int nb = 0; nb < 4; ++nb) bb[nb] = bo[n0 + cn + nb * 16 + l16];

    float* Ew = (float*)smem + w * (16 * 68);
#pragma unroll
    for (int mb = 0; mb < 4; ++mb) {
#pragma unroll
        for (int nb = 0; nb < 4; ++nb)
#pragma unroll
            for (int r = 0; r < 4; ++r)
                Ew[(quad * 4 + r) * 68 + nb * 16 + l16] = acc[mb][nb][r] + bb[nb];
#pragma unroll
        for (int i = 0; i < 4; ++i) {
            int row = i * 4 + (lane >> 4), seg = lane & 15;
            float4 v = *(const float4*)&Ew[row * 68 + seg * 4];
            *(float4*)(out + (size_t)(m0 + rm + mb * 16 + row) * TD + n0 + cn + seg * 4) = v;
        }
    }
}

// ===========================================================================
// Cooperative mega-kernel: prep -> qkv -> attn -> oproj with grid syncs.
// Static LDS 21504 B <= 65536/3, so even a 64KB-per-CU occupancy calculator
// grants 3 blocks/CU -> 768 co-resident blocks.
// ===========================================================================
__global__ __launch_bounds__(256, 3)
void mega_kernel(const float* __restrict__ x,
                 const float* __restrict__ Wq, const float* __restrict__ bq,
                 const float* __restrict__ Wk, const float* __restrict__ bk,
                 const float* __restrict__ Wv, const float* __restrict__ bv,
                 const float* __restrict__ Wo, const float* __restrict__ bo,
                 bf16* xb, bf16* Wqt, bf16* Wkt, bf16* Wvt, bf16* Wot,
                 bf16* Qb, bf16* Kb, bf16* Vtb, bf16* Ob,
                 float* out)
{
    __shared__ __align__(16) char smem[21504];
    const int t = threadIdx.x;
    const int bid = blockIdx.x;
    cg::grid_group grid = cg::this_grid();

    // ---- P0: x cast (all blocks) + W transposes (blocks < 576) ----
    {
        size_t base = (size_t)bid * 8192 + t * 4;
#pragma unroll
        for (int p = 0; p < 8; ++p) {
            float4 v = *(const float4*)(x + base + p * 1024);
            bf16x4 o4;
            o4[0] = (bf16)v.x; o4[1] = (bf16)v.y;
            o4[2] = (bf16)v.z; o4[3] = (bf16)v.w;
            *(bf16x4*)(xb + base + p * 1024) = o4;
        }
        if (bid < 576) {
            const int z = bid / 144, rem = bid % 144;
            const float* W = z == 0 ? Wq : z == 1 ? Wk : z == 2 ? Wv : Wo;
            bf16*       T = z == 0 ? Wqt : z == 1 ? Wkt : z == 2 ? Wvt : Wot;
            const int k0 = (rem % 12) * 64, n0 = (rem / 12) * 64;
            float* Ts = (float*)smem;   // 64 x 65 f32 = 16640 B
            const int rr = t >> 4, cc = (t & 15) * 4;
#pragma unroll
            for (int i = 0; i < 4; ++i) {
                int row = rr + i * 16;
                float4 v = *(const float4*)(W + (size_t)(k0 + row) * TD + n0 + cc);
                Ts[row * 65 + cc]     = v.x; Ts[row * 65 + cc + 1] = v.y;
                Ts[row * 65 + cc + 2] = v.z; Ts[row * 65 + cc + 3] = v.w;
            }
            __syncthreads();
#pragma unroll
            for (int i = 0; i < 4; ++i) {
                int n = rr + i * 16;
                bf16x4 pk;
#pragma unroll
                for (int j = 0; j < 4; ++j) pk[j] = (bf16)Ts[(cc + j) * 65 + n];
                *(bf16x4*)(T + (size_t)(n0 + n) * TD + k0 + cc) = pk;
            }
        }
    }
    __threadfence();
    grid.sync();
    __threadfence();

    // ---- P1: qkv GEMM, 1152 tiles over 768 blocks (2 passes) ----
#pragma unroll 1
    for (int p = 0; p < 2; ++p) {
        int tt = bid + p * 768;
        if (tt < 1152) {
            int which = tt / 384, r = tt % 384;
            qkv_tile32(smem, (r & 63) * 128, (r >> 6) * 128, which,
                       xb, Wqt, Wkt, Wvt, bq, bk, bv, Qb, Kb, Vtb);
        }
    }
    __threadfence();
    grid.sync();
    __threadfence();

    // ---- P2: attention, 768 tiles 1:1 ----
    attn_phase(smem, bid, Qb, Kb, Vtb, Ob);
    __threadfence();
    grid.sync();
    __threadfence();

    // ---- P3: output projection, 384 tiles ----
    if (bid < 384)
        oproj_tile32(smem, (bid & 63) * 128, (bid >> 6) * 128, Ob, Wot, bo, out);
}

// ===========================================================================
// Fallback path: the verified R5 four-kernel pipeline (passing, 217.8 us)
// ===========================================================================
__global__ __launch_bounds__(256)
void prep_kernel(const float* __restrict__ x, bf16* __restrict__ xb,
                 const float* __restrict__ W0, const float* __restrict__ W1,
                 const float* __restrict__ W2, const float* __restrict__ W3,
                 bf16* __restrict__ T0, bf16* __restrict__ T1,
                 bf16* __restrict__ T2, bf16* __restrict__ T3)
{
    __shared__ float Ts[64][65];
    const int t = threadIdx.x;

    if (blockIdx.x < 6144) {
        size_t i = ((size_t)blockIdx.x * 256 + t) * 4;
        float4 v = *(const float4*)(x + i);
        bf16x4 o;
        o[0] = (bf16)v.x; o[1] = (bf16)v.y; o[2] = (bf16)v.z; o[3] = (bf16)v.w;
        *(bf16x4*)(xb + i) = o;
        return;
    }

    const int bid = blockIdx.x - 6144;
    const int z = bid / 144, rem = bid % 144;
    const float* W = z == 0 ? W0 : z == 1 ? W1 : z == 2 ? W2 : W3;
    bf16*       T = z == 0 ? T0 : z == 1 ? T1 : z == 2 ? T2 : T3;
    const int k0 = (rem % 12) * 64, n0 = (rem / 12) * 64;
    const int rr = t >> 4, cc = (t & 15) * 4;
#pragma unroll
    for (int i = 0; i < 4; ++i) {
        int row = rr + i * 16;
        float4 v = *(const float4*)(W + (size_t)(k0 + row) * TD + n0 + cc);
        Ts[row][cc] = v.x; Ts[row][cc + 1] = v.y;
        Ts[row][cc + 2] = v.z; Ts[row][cc + 3] = v.w;
    }
    __syncthreads();
#pragma unroll
    for (int i = 0; i < 4; ++i) {
        int n = rr + i * 16;
        bf16x4 pk;
#pragma unroll
        for (int j = 0; j < 4; ++j) pk[j] = (bf16)Ts[cc + j][n];
        *(bf16x4*)(T + (size_t)(n0 + n) * TD + k0 + cc) = pk;
    }
}

__global__ __launch_bounds__(256)
void qkv_gemm(const bf16* __restrict__ xb,
              const bf16* __restrict__ Wqt, const bf16* __restrict__ Wkt,
              const bf16* __restrict__ Wvt,
              const float* __restrict__ bq, const float* __restrict__ bk,
              const float* __restrict__ bv,
              bf16* __restrict__ Q, bf16* __restrict__ K, bf16* __restrict__ Vt)
{
    __shared__ __align__(16) bf16 SM[2 * 128 * 64];
    bf16* As = SM;
    bf16* Bs = SM + 128 * 64;

    const int t = threadIdx.x;
    const int lane = t & 63, w = t >> 6;
    const int quad = lane >> 4, l16 = lane & 15;
    const int m0 = blockIdx.x * 128;
    const int n0 = blockIdx.y * 128;
    const int which = blockIdx.z;
    const bf16*  W    = which == 0 ? Wqt : which == 1 ? Wkt : Wvt;
    const float* bias = which == 0 ? bq  : which == 1 ? bk  : bv;
    const float scale = which == 0 ? QSCALE : 1.0f;
    const int rm = (w >> 1) * 64, cn = (w & 1) * 64;

    floatx4 acc[4][4];
#pragma unroll
    for (int i = 0; i < 4; ++i)
#pragma unroll
        for (int j = 0; j < 4; ++j) acc[i][j] = (floatx4){0.f, 0.f, 0.f, 0.f};

    const bf16* gA[4];
    const bf16* gB[4];
#pragma unroll
    for (int i = 0; i < 4; ++i) {
        int n = t + i * 256, r = n >> 3, s = ((n & 7) ^ (r & 7)) * 8;
        gA[i] = xb + (size_t)(m0 + r) * TD + s;
        gB[i] = W + (size_t)(n0 + r) * TD + s;
    }

    for (int kk = 0; kk < TD; kk += 64) {
#pragma unroll
        for (int i = 0; i < 4; ++i) {
            gl_lds16(gA[i] + kk, As + t * 8 + i * 2048);
            gl_lds16(gB[i] + kk, Bs + t * 8 + i * 2048);
        }
        __syncthreads();
#pragma unroll
        for (int ks = 0; ks < 2; ++ks) {
            bf16x8 af[4], bfr[4];
#pragma unroll
            for (int mb = 0; mb < 4; ++mb) {
                int r = rm + mb * 16 + l16;
                af[mb] = *(const bf16x8*)&As[r * 64 + (((ks * 4 + quad) ^ (r & 7)) * 8)];
            }
#pragma unroll
            for (int nb = 0; nb < 4; ++nb) {
                int r = cn + nb * 16 + l16;
                bfr[nb] = *(const bf16x8*)&Bs[r * 64 + (((ks * 4 + quad) ^ (r & 7)) * 8)];
            }
#pragma unroll
            for (int mb = 0; mb < 4; ++mb)
#pragma unroll
                for (int nb = 0; nb < 4; ++nb)
                    acc[mb][nb] = MFMA16(af[mb], bfr[nb], acc[mb][nb]);
        }
        __syncthreads();
    }

    float bsc[4];
#pragma unroll
    for (int nb = 0; nb < 4; ++nb)
        bsc[nb] = bias[n0 + cn + nb * 16 + l16] * scale;

    const int token0 = m0 + rm;
    const int b  = token0 >> 11;
    const int l0 = token0 & (TL - 1);
    const int h  = (n0 + cn) >> 6;
    const int bh = b * NH + h;
    bf16* Ew = SM + w * (16 * 72);

    if (which < 2) {
        bf16* gp = (which == 0 ? Q : K) + ((size_t)bh * TL + l0) * HD;
#pragma unroll
        for (int mb = 0; mb < 4; ++mb) {
#pragma unroll
            for (int nb = 0; nb < 4; ++nb)
#pragma unroll
                for (int r = 0; r < 4; ++r)
                    Ew[(quad * 4 + r) * 72 + nb * 16 + l16] =
                        (bf16)(acc[mb][nb][r] * scale + bsc[nb]);
#pragma unroll
            for (int i = 0; i < 2; ++i) {
                int row = i * 8 + (lane >> 3), seg = lane & 7;
                bf16x8 v = *(const bf16x8*)&Ew[row * 72 + seg * 8];
                *(bf16x8*)(gp + (size_t)(mb * 16 + row) * HD + seg * 8) = v;
            }
        }
    } else {
#pragma unroll
        for (int nb = 0; nb < 4; ++nb) {
#pragma unroll
            for (int mb = 0; mb < 4; ++mb) {
                bf16x4 pk;
#pragma unroll
                for (int r = 0; r < 4; ++r) pk[r] = (bf16)(acc[mb][nb][r] + bsc[nb]);
                *(bf16x4*)&Ew[l16 * 72 + mb * 16 + quad * 4] = pk;
            }
#pragma unroll
            for (int i = 0; i < 2; ++i) {
                int row = i * 8 + (lane >> 3), seg = lane & 7;
                bf16x8 v = *(const bf16x8*)&Ew[row * 72 + seg * 8];
                *(bf16x8*)(Vt + ((size_t)bh * HD + nb * 16 + row) * TL + l0 + seg * 8) = v;
            }
        }
    }
}

__global__ __launch_bounds__(256)
void attn_kernel(const bf16* __restrict__ Q, const bf16* __restrict__ K,
                 const bf16* __restrict__ Vt, bf16* __restrict__ O)
{
    __shared__ __align__(16) char smem[16384];
    const int n = blockIdx.y * gridDim.x + blockIdx.x;
    attn_phase(smem, n, Q, K, Vt, O);
}

__global__ __launch_bounds__(256)
void oproj_gemm(const bf16* __restrict__ A, const bf16* __restrict__ Wt,
                const float* __restrict__ bo, float* __restrict__ out)
{
    __shared__ __align__(16) bf16 SM[2 * 128 * 64];
    bf16* As = SM;
    bf16* Bs = SM + 128 * 64;

    const int t = threadIdx.x;
    const int lane = t & 63, w = t >> 6;
    const int quad = lane >> 4, l16 = lane & 15;
    const int m0 = blockIdx.x * 128;
    const int n0 = blockIdx.y * 128;
    const int rm = (w >> 1) * 64, cn = (w & 1) * 64;

    floatx4 acc[4][4];
#pragma unroll
    for (int i = 0; i < 4; ++i)
#pragma unroll
        for (int j = 0; j < 4; ++j) acc[i][j] = (floatx4){0.f, 0.f, 0.f, 0.f};

    const bf16* gA[4];
    const bf16* gB[4];
#pragma unroll
    for (int i = 0; i < 4; ++i) {
        int n = t + i * 256, r = n >> 3, s = ((n & 7) ^ (r & 7)) * 8;
        gA[i] = A + (size_t)(m0 + r) * TD + s;
        gB[i] = Wt + (size_t)(n0 + r) * TD + s;
    }

    for (int kk = 0; kk < TD; kk += 64) {
#pragma unroll
        for (int i = 0; i < 4; ++i) {
            gl_lds16(gA[i] + kk, As + t * 8 + i * 2048);
            gl_lds16(gB[i] + kk, Bs + t * 8 + i * 2048);
        }
        __syncthreads();
#pragma unroll
        for (int ks = 0; ks < 2; ++ks) {
            bf16x8 af[4], bfr[4];
#pragma unroll
            for (int mb = 0; mb < 4; ++mb) {
                int r = rm + mb * 16 + l16;
                af[mb] = *(const bf16x8*)&As[r * 64 + (((ks * 4 + quad) ^ (r & 7)) * 8)];
            }
#pragma unroll
            for (int nb = 0; nb < 4; ++nb) {
                int r = cn + nb * 16 + l16;
                bfr[nb] = *(const bf16x8*)&Bs[r * 64 + (((ks * 4 + quad) ^ (r & 7)) * 8)];
            }
#pragma unroll
            for (int mb = 0; mb < 4; ++mb)
#pragma unroll
                for (int nb = 0; nb < 4; ++nb)
                    acc[mb][nb] = MFMA16(af[mb], bfr[nb], acc[mb][nb]);
        }
        __syncthreads();
    }

    float bb[4];
#pragma unroll
    for (int nb = 0; nb < 4; ++nb) bb[nb] = bo[n0 + cn + nb * 16 + l16];

    float* Ew = (float*)SM + w * (16 * 68);
#pragma unroll
    for (int mb = 0; mb < 4; ++mb) {
#pragma unroll
        for (int nb = 0; nb < 4; ++nb)
#pragma unroll
            for (int r = 0; r < 4; ++r)
                Ew[(quad * 4 + r) * 68 + nb * 16 + l16] = acc[mb][nb][r] + bb[nb];
#pragma unroll
        for (int i = 0; i < 4; ++i) {
            int row = i * 4 + (lane >> 4), seg = lane & 15;
            float4 v = *(const float4*)&Ew[row * 68 + seg * 4];
            *(float4*)(out + (size_t)(m0 + rm + mb * 16 + row) * TD + n0 + cn + seg * 4) = v;
        }
    }
}

// ---------------------------------------------------------------------------
extern "C" void kernel_launch(void* const* d_in, const int* in_sizes, int n_in,
                              void* d_out, int out_size, void* d_ws, size_t ws_size,
                              hipStream_t stream)
{
    const float* x  = (const float*)d_in[0];
    const float* Wq = (const float*)d_in[1];
    const float* bq = (const float*)d_in[2];
    const float* Wk = (const float*)d_in[3];
    const float* bk = (const float*)d_in[4];
    const float* Wv = (const float*)d_in[5];
    const float* bv = (const float*)d_in[6];
    const float* Wo = (const float*)d_in[7];
    const float* bo = (const float*)d_in[8];

    const size_t NXE = (size_t)MTOT * TD;    // 6,291,456
    const size_t NWE = (size_t)TD * TD;      // 589,824

    bf16* xb  = (bf16*)d_ws;
    bf16* Wqt = xb + NXE;
    bf16* Wkt = Wqt + NWE;
    bf16* Wvt = Wkt + NWE;
    bf16* Wot = Wvt + NWE;
    bf16* Qb  = Wot + NWE;
    bf16* Kb  = Qb + NXE;
    bf16* Vtb = Kb + NXE;
    bf16* Ob  = Vtb + NXE;
    float* outp = (float*)d_out;

    // Decide once: can 768 mega-kernel blocks be co-resident?
    static int use_coop = -1;
    if (use_coop < 0) {
        int coop = 0, ncu = 0, nb = 0;
        hipDeviceGetAttribute(&coop, hipDeviceAttributeCooperativeLaunch, 0);
        hipDeviceGetAttribute(&ncu, hipDeviceAttributeMultiprocessorCount, 0);
        hipOccupancyMaxActiveBlocksPerMultiprocessor(&nb, mega_kernel, 256, 0);
        use_coop = (coop && (long)nb * ncu >= 768) ? 1 : 0;
    }

    if (use_coop) {
        void* args[] = {
            (void*)&x,
            (void*)&Wq, (void*)&bq, (void*)&Wk, (void*)&bk,
            (void*)&Wv, (void*)&bv, (void*)&Wo, (void*)&bo,
            (void*)&xb, (void*)&Wqt, (void*)&Wkt, (void*)&Wvt, (void*)&Wot,
            (void*)&Qb, (void*)&Kb, (void*)&Vtb, (void*)&Ob,
            (void*)&outp
        };
        hipError_t e = hipLaunchCooperativeKernel((const void*)mega_kernel,
                                                  dim3(768), dim3(256), args,
                                                  0, stream);
        if (e == hipSuccess) return;
        use_coop = 0;   // fall through to the verified 4-kernel path
    }

    prep_kernel<<<6144 + 576, 256, 0, stream>>>(x, xb, Wq, Wk, Wv, Wo,
                                                Wqt, Wkt, Wvt, Wot);
    qkv_gemm<<<dim3(MTOT / 128, TD / 128, 3), 256, 0, stream>>>(
        xb, Wqt, Wkt, Wvt, bq, bk, bv, Qb, Kb, Vtb);
    attn_kernel<<<dim3(TL / 128, NB * NH), 256, 0, stream>>>(Qb, Kb, Vtb, Ob);
    oproj_gemm<<<dim3(MTOT / 128, TD / 128), 256, 0, stream>>>(Ob, Wot, bo,
                                                               (float*)d_out);
}

// Round 8
// 215.397 us; speedup vs baseline: 1.1525x; 1.0030x over previous
//
#include <hip/hip_runtime.h>
#include <math.h>

#define TL 2048
#define TD 768
#define NH 12
#define HD 64
#define NB 4
#define MTOT (NB * TL)   // 8192

typedef __bf16 bf16;
typedef __attribute__((ext_vector_type(4))) __bf16 bf16x4;
typedef __attribute__((ext_vector_type(8))) __bf16 bf16x8;
typedef __attribute__((ext_vector_type(4))) float floatx4;

// Q pre-scale: 1/sqrt(64) * log2(e)  (softmax computed in exp2 domain)
#define QSCALE 0.18033688011112042f

#define MFMA16(A, B, C) __builtin_amdgcn_mfma_f32_16x16x32_bf16(A, B, C, 0, 0, 0)

__device__ __forceinline__ void gl_lds16(const void* g, void* l) {
    __builtin_amdgcn_global_load_lds(
        (const __attribute__((address_space(1))) void*)g,
        (__attribute__((address_space(3))) void*)l, 16, 0, 0);
}

__device__ __forceinline__ floatx4 exp2x4(floatx4 a) {
    floatx4 r;
    r.x = __builtin_amdgcn_exp2f(a.x);
    r.y = __builtin_amdgcn_exp2f(a.y);
    r.z = __builtin_amdgcn_exp2f(a.z);
    r.w = __builtin_amdgcn_exp2f(a.w);
    return r;
}

// Inverse of the key->LDS-row permutation that makes QK^T's C-registers
// coincide with PV's A-fragment layout. Row r holds key kperm_inv(r).
__device__ __forceinline__ int kperm_inv(int r) {
    return (r & 35) | (((r >> 2) & 3) << 3) | (((r >> 4) & 1) << 2);
}

// ---------------------------------------------------------------------------
// prep: fused x fp32->bf16 cast (blocks 0..6143) + W transpose->bf16
// (blocks 6144..6719).
// ---------------------------------------------------------------------------
__global__ __launch_bounds__(256)
void prep_kernel(const float* __restrict__ x, bf16* __restrict__ xb,
                 const float* __restrict__ W0, const float* __restrict__ W1,
                 const float* __restrict__ W2, const float* __restrict__ W3,
                 bf16* __restrict__ T0, bf16* __restrict__ T1,
                 bf16* __restrict__ T2, bf16* __restrict__ T3)
{
    __shared__ float Ts[64][65];
    const int t = threadIdx.x;

    if (blockIdx.x < 6144) {
        size_t i = ((size_t)blockIdx.x * 256 + t) * 4;
        float4 v = *(const float4*)(x + i);
        bf16x4 o;
        o[0] = (bf16)v.x; o[1] = (bf16)v.y; o[2] = (bf16)v.z; o[3] = (bf16)v.w;
        *(bf16x4*)(xb + i) = o;
        return;
    }

    const int bid = blockIdx.x - 6144;          // 0..575
    const int z = bid / 144, rem = bid % 144;
    const float* W = z == 0 ? W0 : z == 1 ? W1 : z == 2 ? W2 : W3;
    bf16*       T = z == 0 ? T0 : z == 1 ? T1 : z == 2 ? T2 : T3;
    const int k0 = (rem % 12) * 64, n0 = (rem / 12) * 64;
    const int rr = t >> 4, cc = (t & 15) * 4;
#pragma unroll
    for (int i = 0; i < 4; ++i) {
        int row = rr + i * 16;
        float4 v = *(const float4*)(W + (size_t)(k0 + row) * TD + n0 + cc);
        Ts[row][cc] = v.x; Ts[row][cc + 1] = v.y;
        Ts[row][cc + 2] = v.z; Ts[row][cc + 3] = v.w;
    }
    __syncthreads();
#pragma unroll
    for (int i = 0; i < 4; ++i) {
        int n = rr + i * 16;
        bf16x4 pk;
#pragma unroll
        for (int j = 0; j < 4; ++j) pk[j] = (bf16)Ts[cc + j][n];
        *(bf16x4*)(T + (size_t)(n0 + n) * TD + k0 + cc) = pk;
    }
}

// ---------------------------------------------------------------------------
// QKV GEMM: 128x128 tile, BK=64, XOR-swizzled LDS, global_load_lds staging,
// LDS-bounce epilogue aliased on As/Bs (32 KB total LDS).
// XCD-aware M-stripe swizzle: mt = ((x&7)<<3)|(x>>3) gives XCD j (= x%8,
// since 64 and 384 are both 0 mod 8 in the dispatch index) the contiguous
// M-tiles [8j,8j+8) for every (n0,which) -> its A-stripe (1.6 MB) + W stay
// L2-resident, shortening the per-iteration vmcnt drain.
// ---------------------------------------------------------------------------
__global__ __launch_bounds__(256)
void qkv_gemm(const bf16* __restrict__ xb,
              const bf16* __restrict__ Wqt, const bf16* __restrict__ Wkt,
              const bf16* __restrict__ Wvt,
              const float* __restrict__ bq, const float* __restrict__ bk,
              const float* __restrict__ bv,
              bf16* __restrict__ Q, bf16* __restrict__ K, bf16* __restrict__ Vt)
{
    __shared__ __align__(16) bf16 SM[2 * 128 * 64];   // As | Bs ; epilogue reuses
    bf16* As = SM;
    bf16* Bs = SM + 128 * 64;

    const int t = threadIdx.x;
    const int lane = t & 63, w = t >> 6;
    const int quad = lane >> 4, l16 = lane & 15;
    const int mt = ((blockIdx.x & 7) << 3) | (blockIdx.x >> 3);   // XCD stripe
    const int m0 = mt * 128;
    const int n0 = blockIdx.y * 128;
    const int which = blockIdx.z;
    const bf16*  W    = which == 0 ? Wqt : which == 1 ? Wkt : Wvt;
    const float* bias = which == 0 ? bq  : which == 1 ? bk  : bv;
    const float scale = which == 0 ? QSCALE : 1.0f;
    const int rm = (w >> 1) * 64, cn = (w & 1) * 64;

    floatx4 acc[4][4];
#pragma unroll
    for (int i = 0; i < 4; ++i)
#pragma unroll
        for (int j = 0; j < 4; ++j) acc[i][j] = (floatx4){0.f, 0.f, 0.f, 0.f};

    // staging sources: slot n = t + i*256; row = n>>3; seg = (n&7)^(row&7)
    const bf16* gA[4];
    const bf16* gB[4];
#pragma unroll
    for (int i = 0; i < 4; ++i) {
        int n = t + i * 256, r = n >> 3, s = ((n & 7) ^ (r & 7)) * 8;
        gA[i] = xb + (size_t)(m0 + r) * TD + s;
        gB[i] = W + (size_t)(n0 + r) * TD + s;
    }

    for (int kk = 0; kk < TD; kk += 64) {
#pragma unroll
        for (int i = 0; i < 4; ++i) {
            gl_lds16(gA[i] + kk, As + t * 8 + i * 2048);
            gl_lds16(gB[i] + kk, Bs + t * 8 + i * 2048);
        }
        __syncthreads();
#pragma unroll
        for (int ks = 0; ks < 2; ++ks) {
            bf16x8 af[4], bfr[4];
#pragma unroll
            for (int mb = 0; mb < 4; ++mb) {
                int r = rm + mb * 16 + l16;
                af[mb] = *(const bf16x8*)&As[r * 64 + (((ks * 4 + quad) ^ (r & 7)) * 8)];
            }
#pragma unroll
            for (int nb = 0; nb < 4; ++nb) {
                int r = cn + nb * 16 + l16;
                bfr[nb] = *(const bf16x8*)&Bs[r * 64 + (((ks * 4 + quad) ^ (r & 7)) * 8)];
            }
#pragma unroll
            for (int mb = 0; mb < 4; ++mb)
#pragma unroll
                for (int nb = 0; nb < 4; ++nb)
                    acc[mb][nb] = MFMA16(af[mb], bfr[nb], acc[mb][nb]);
        }
        __syncthreads();
    }

    float bsc[4];
#pragma unroll
    for (int nb = 0; nb < 4; ++nb)
        bsc[nb] = bias[n0 + cn + nb * 16 + l16] * scale;

    const int token0 = m0 + rm;
    const int b  = token0 >> 11;
    const int l0 = token0 & (TL - 1);
    const int h  = (n0 + cn) >> 6;
    const int bh = b * NH + h;
    // per-wave epilogue bounce aliased onto SM (K-loop LDS reads retired at
    // the final barrier; regions are wave-private)
    bf16* Ew = SM + w * (16 * 72);

    if (which < 2) {
        bf16* gp = (which == 0 ? Q : K) + ((size_t)bh * TL + l0) * HD;
#pragma unroll
        for (int mb = 0; mb < 4; ++mb) {
#pragma unroll
            for (int nb = 0; nb < 4; ++nb)
#pragma unroll
                for (int r = 0; r < 4; ++r)
                    Ew[(quad * 4 + r) * 72 + nb * 16 + l16] =
                        (bf16)(acc[mb][nb][r] * scale + bsc[nb]);
#pragma unroll
            for (int i = 0; i < 2; ++i) {
                int row = i * 8 + (lane >> 3), seg = lane & 7;
                bf16x8 v = *(const bf16x8*)&Ew[row * 72 + seg * 8];
                *(bf16x8*)(gp + (size_t)(mb * 16 + row) * HD + seg * 8) = v;
            }
        }
    } else {
#pragma unroll
        for (int nb = 0; nb < 4; ++nb) {
#pragma unroll
            for (int mb = 0; mb < 4; ++mb) {
                bf16x4 pk;
#pragma unroll
                for (int r = 0; r < 4; ++r) pk[r] = (bf16)(acc[mb][nb][r] + bsc[nb]);
                *(bf16x4*)&Ew[l16 * 72 + mb * 16 + quad * 4] = pk;
            }
#pragma unroll
            for (int i = 0; i < 2; ++i) {
                int row = i * 8 + (lane >> 3), seg = lane & 7;
                bf16x8 v = *(const bf16x8*)&Ew[row * 72 + seg * 8];
                *(bf16x8*)(Vt + ((size_t)bh * HD + nb * 16 + row) * TL + l0 + seg * 8) = v;
            }
        }
    }
}

// ---------------------------------------------------------------------------
// MFMA flash attention v5 (R0-exact, measured 70-73 us / 733 TF): P never
// touches LDS; K/V staged via global_load_lds with the key permutation folded
// into the per-lane global source address; XOR segment swizzle (0 conflicts).
// ---------------------------------------------------------------------------
__global__ __launch_bounds__(256)
void attn_kernel(const bf16* __restrict__ Q, const bf16* __restrict__ K,
                 const bf16* __restrict__ Vt, bf16* __restrict__ O)
{
    __shared__ __align__(16) bf16 Ks[64 * 64];   // [kperm(key)][seg^(row&7)]
    __shared__ __align__(16) bf16 Vs[64 * 64];   // [d][seg^(d&7)] over keys

    const int t = threadIdx.x;
    const int lane = t & 63, w = t >> 6;
    const int quad = lane >> 4, l16 = lane & 15;

    // XCD-aware swizzle: blocks on the same XCD (n%8) share one bh's K/V
    const int n = blockIdx.y * gridDim.x + blockIdx.x;   // 0..767
    const int xcd = n & 7, s = n >> 3;                   // s: 0..95
    const int bh = xcd * 6 + (s >> 4);
    const int q0 = (s & 15) * 128;

    const bf16* Qb = Q + (size_t)bh * TL * HD;
    const bf16* Kb = K + (size_t)bh * TL * HD;
    const bf16* Vb = Vt + (size_t)bh * HD * TL;

    const int qw = q0 + w * 32;
    bf16x8 qf[2][2];
#pragma unroll
    for (int mb = 0; mb < 2; ++mb)
#pragma unroll
        for (int ks = 0; ks < 2; ++ks)
            qf[mb][ks] = *(const bf16x8*)(Qb + (size_t)(qw + mb * 16 + l16) * HD
                                          + ks * 32 + quad * 8);

    float lrow[2] = {0.f, 0.f};      // per-lane partial row-sum for q = mb*16+l16
    floatx4 o[2][4];
#pragma unroll
    for (int mb = 0; mb < 2; ++mb)
#pragma unroll
        for (int db = 0; db < 4; ++db) o[mb][db] = (floatx4){0.f, 0.f, 0.f, 0.f};

    // staging sources: slots n = t (i=0), t+256 (i=1); row = n>>3, 8 slots/row
    const bf16* gK[2];
    const bf16* gV[2];
#pragma unroll
    for (int i = 0; i < 2; ++i) {
        int nn = t + i * 256, r = nn >> 3, sg = ((nn & 7) ^ (r & 7)) * 8;
        gK[i] = Kb + (size_t)kperm_inv(r) * HD + sg;   // + k0*HD per step
        gV[i] = Vb + (size_t)r * TL + sg;              // + k0 per step
    }

    for (int kt = 0; kt < TL / 64; ++kt) {
        const int k0 = kt * 64;
        __syncthreads();
#pragma unroll
        for (int i = 0; i < 2; ++i) {
            gl_lds16(gK[i] + (size_t)k0 * HD, Ks + t * 8 + i * 2048);
            gl_lds16(gV[i] + k0,              Vs + t * 8 + i * 2048);
        }
        __syncthreads();

        // S^T = K' Q^T : lane holds S[q=mb*16+l16][key=32(nb>>1)+4(nb&1)+8quad+r]
        floatx4 s2[2][4];
#pragma unroll
        for (int nb = 0; nb < 4; ++nb) {
            int r = nb * 16 + l16;
            bf16x8 kf0 = *(const bf16x8*)&Ks[r * 64 + ((quad ^ (r & 7)) * 8)];
            bf16x8 kf1 = *(const bf16x8*)&Ks[r * 64 + (((4 + quad) ^ (r & 7)) * 8)];
#pragma unroll
            for (int mb = 0; mb < 2; ++mb) {
                floatx4 a = (floatx4){0.f, 0.f, 0.f, 0.f};
                a = MFMA16(kf0, qf[mb][0], a);
                a = MFMA16(kf1, qf[mb][1], a);
                s2[mb][nb] = a;
            }
        }

        // P = 2^S in-register; repack into PV A-fragments (keys ks*32+8quad+j)
        bf16x8 pA[2][2];
#pragma unroll
        for (int mb = 0; mb < 2; ++mb) {
#pragma unroll
            for (int ks = 0; ks < 2; ++ks) {
                floatx4 p0 = exp2x4(s2[mb][2 * ks]);
                floatx4 p1 = exp2x4(s2[mb][2 * ks + 1]);
                lrow[mb] += (p0.x + p0.y + p0.z + p0.w) + (p1.x + p1.y + p1.z + p1.w);
                bf16x8 pk;
                pk[0] = (bf16)p0.x; pk[1] = (bf16)p0.y; pk[2] = (bf16)p0.z; pk[3] = (bf16)p0.w;
                pk[4] = (bf16)p1.x; pk[5] = (bf16)p1.y; pk[6] = (bf16)p1.z; pk[7] = (bf16)p1.w;
                pA[mb][ks] = pk;
            }
        }

        // O += P V
#pragma unroll
        for (int ks = 0; ks < 2; ++ks) {
#pragma unroll
            for (int db = 0; db < 4; ++db) {
                int r = db * 16 + l16;
                bf16x8 vf = *(const bf16x8*)&Vs[r * 64 + (((ks * 4 + quad) ^ (r & 7)) * 8)];
#pragma unroll
                for (int mb = 0; mb < 2; ++mb)
                    o[mb][db] = MFMA16(pA[mb][ks], vf, o[mb][db]);
            }
        }
    }

    // epilogue: complete row-sums (reduce over the 4 quads), normalize, store.
    const int b = bh / NH, h = bh % NH;
#pragma unroll
    for (int mb = 0; mb < 2; ++mb) {
        lrow[mb] += __shfl_xor(lrow[mb], 16);
        lrow[mb] += __shfl_xor(lrow[mb], 32);   // now lane holds sum for q=mb*16+l16
        floatx4 inv;
#pragma unroll
        for (int r = 0; r < 4; ++r)
            inv[r] = 1.0f / __shfl(lrow[mb], (lane & 48) | (quad * 4 + r));
#pragma unroll
        for (int db = 0; db < 4; ++db)
#pragma unroll
            for (int r = 0; r < 4; ++r) {
                int l = qw + mb * 16 + quad * 4 + r;
                O[((size_t)b * TL + l) * TD + h * HD + db * 16 + l16] =
                    (bf16)(o[mb][db][r] * inv[r]);
            }
    }
}

// ---------------------------------------------------------------------------
// Output projection: out fp32 = O_bf16 @ Wo + bo. Same XCD M-stripe swizzle:
// per-XCD working set = 1.6 MB A-stripe + 1.2 MB Wot -> fully L2-resident.
// ---------------------------------------------------------------------------
__global__ __launch_bounds__(256)
void oproj_gemm(const bf16* __restrict__ A, const bf16* __restrict__ Wt,
                const float* __restrict__ bo, float* __restrict__ out)
{
    __shared__ __align__(16) bf16 SM[2 * 128 * 64];   // As | Bs ; epilogue reuses
    bf16* As = SM;
    bf16* Bs = SM + 128 * 64;

    const int t = threadIdx.x;
    const int lane = t & 63, w = t >> 6;
    const int quad = lane >> 4, l16 = lane & 15;
    const int mt = ((blockIdx.x & 7) << 3) | (blockIdx.x >> 3);   // XCD stripe
    const int m0 = mt * 128;
    const int n0 = blockIdx.y * 128;
    const int rm = (w >> 1) * 64, cn = (w & 1) * 64;

    floatx4 acc[4][4];
#pragma unroll
    for (int i = 0; i < 4; ++i)
#pragma unroll
        for (int j = 0; j < 4; ++j) acc[i][j] = (floatx4){0.f, 0.f, 0.f, 0.f};

    const bf16* gA[4];
    const bf16* gB[4];
#pragma unroll
    for (int i = 0; i < 4; ++i) {
        int n = t + i * 256, r = n >> 3, s = ((n & 7) ^ (r & 7)) * 8;
        gA[i] = A + (size_t)(m0 + r) * TD + s;
        gB[i] = Wt + (size_t)(n0 + r) * TD + s;
    }

    for (int kk = 0; kk < TD; kk += 64) {
#pragma unroll
        for (int i = 0; i < 4; ++i) {
            gl_lds16(gA[i] + kk, As + t * 8 + i * 2048);
            gl_lds16(gB[i] + kk, Bs + t * 8 + i * 2048);
        }
        __syncthreads();
#pragma unroll
        for (int ks = 0; ks < 2; ++ks) {
            bf16x8 af[4], bfr[4];
#pragma unroll
            for (int mb = 0; mb < 4; ++mb) {
                int r = rm + mb * 16 + l16;
                af[mb] = *(const bf16x8*)&As[r * 64 + (((ks * 4 + quad) ^ (r & 7)) * 8)];
            }
#pragma unroll
            for (int nb = 0; nb < 4; ++nb) {
                int r = cn + nb * 16 + l16;
                bfr[nb] = *(const bf16x8*)&Bs[r * 64 + (((ks * 4 + quad) ^ (r & 7)) * 8)];
            }
#pragma unroll
            for (int mb = 0; mb < 4; ++mb)
#pragma unroll
                for (int nb = 0; nb < 4; ++nb)
                    acc[mb][nb] = MFMA16(af[mb], bfr[nb], acc[mb][nb]);
        }
        __syncthreads();
    }

    float bb[4];
#pragma unroll
    for (int nb = 0; nb < 4; ++nb) bb[nb] = bo[n0 + cn + nb * 16 + l16];

    // per-wave f32 bounce aliased onto SM (16*68 floats per wave)
    float* Ew = (float*)SM + w * (16 * 68);
#pragma unroll
    for (int mb = 0; mb < 4; ++mb) {
#pragma unroll
        for (int nb = 0; nb < 4; ++nb)
#pragma unroll
            for (int r = 0; r < 4; ++r)
                Ew[(quad * 4 + r) * 68 + nb * 16 + l16] = acc[mb][nb][r] + bb[nb];
#pragma unroll
        for (int i = 0; i < 4; ++i) {
            int row = i * 4 + (lane >> 4), seg = lane & 15;
            float4 v = *(const float4*)&Ew[row * 68 + seg * 4];
            *(float4*)(out + (size_t)(m0 + rm + mb * 16 + row) * TD + n0 + cn + seg * 4) = v;
        }
    }
}

// ---------------------------------------------------------------------------
extern "C" void kernel_launch(void* const* d_in, const int* in_sizes, int n_in,
                              void* d_out, int out_size, void* d_ws, size_t ws_size,
                              hipStream_t stream)
{
    const float* x  = (const float*)d_in[0];
    const float* Wq = (const float*)d_in[1];
    const float* bq = (const float*)d_in[2];
    const float* Wk = (const float*)d_in[3];
    const float* bk = (const float*)d_in[4];
    const float* Wv = (const float*)d_in[5];
    const float* bv = (const float*)d_in[6];
    const float* Wo = (const float*)d_in[7];
    const float* bo = (const float*)d_in[8];

    const size_t NXE = (size_t)MTOT * TD;    // 6,291,456
    const size_t NWE = (size_t)TD * TD;      // 589,824

    bf16* xb  = (bf16*)d_ws;
    bf16* Wqt = xb + NXE;
    bf16* Wkt = Wqt + NWE;
    bf16* Wvt = Wkt + NWE;
    bf16* Wot = Wvt + NWE;
    bf16* Qb  = Wot + NWE;
    bf16* Kb  = Qb + NXE;
    bf16* Vtb = Kb + NXE;
    bf16* Ob  = Vtb + NXE;

    prep_kernel<<<6144 + 576, 256, 0, stream>>>(x, xb, Wq, Wk, Wv, Wo,
                                                Wqt, Wkt, Wvt, Wot);
    qkv_gemm<<<dim3(MTOT / 128, TD / 128, 3), 256, 0, stream>>>(
        xb, Wqt, Wkt, Wvt, bq, bk, bv, Qb, Kb, Vtb);
    attn_kernel<<<dim3(TL / 128, NB * NH), 256, 0, stream>>>(Qb, Kb, Vtb, Ob);
    oproj_gemm<<<dim3(MTOT / 128, TD / 128), 256, 0, stream>>>(Ob, Wot, bo,
                                                               (float*)d_out);
}